// Round 3
// baseline (217.473 us; speedup 1.0000x reference)
//
#include <hip/hip_runtime.h>
#include <hip/hip_bf16.h>

#define T_SEQ 2048
#define D_DIM 1024
#define NB 4

typedef __attribute__((ext_vector_type(8))) short short8;
typedef __attribute__((ext_vector_type(4))) float f32x4;

__device__ __forceinline__ unsigned short f2bf(float f) {
    unsigned int u = __float_as_uint(f);
    u = (u + 0x7FFFu + ((u >> 16) & 1u)) >> 16;
    return (unsigned short)u;
}

__global__ void cast_kernel(const float4* __restrict__ in, ushort4* __restrict__ out, int n4) {
    int i = blockIdx.x * 256 + threadIdx.x;
    if (i < n4) {
        float4 f = in[i];
        ushort4 o;
        o.x = f2bf(f.x); o.y = f2bf(f.y); o.z = f2bf(f.z); o.w = f2bf(f.w);
        out[i] = o;
    }
}

#define GLD(gp, lp) __builtin_amdgcn_global_load_lds( \
    (__attribute__((address_space(1))) void*)(gp), \
    (__attribute__((address_space(3))) void*)(lp), 16, 0, 0)

// Tile: (MFR*32) x 128, BK=32, 4 waves as 2x2, each wave (MFR*16) x 64 frags,
// double-buffered LDS (stage k+1 while computing k; one barrier per K-step).
// A: [M,K] row-major bf16. B: [N,K] row-major bf16 (B-transposed layout).
template<int MFR>
__device__ __forceinline__ void gemm_core_t(const unsigned short* __restrict__ A,
                                            const unsigned short* __restrict__ B,
                                            int lda, int ldb, int bm, int bn, int kend,
                                            f32x4 acc[MFR][4]) {
    constexpr int AROWS = MFR * 32;
    __shared__ __align__(16) unsigned short As[2][AROWS * 32];
    __shared__ __align__(16) unsigned short Bs[2][128 * 32];
    const int tid  = threadIdx.x;
    const int lane = tid & 63;
    const int wave = tid >> 6;
    const int wm   = (wave >> 1) * (MFR * 16);
    const int wn   = (wave & 1) * 64;
    const int lo   = lane & 15;
    const int hi8  = (lane >> 4) * 8;
    const int r0   = tid >> 2;          // staging row 0..63
    const int q0   = (tid & 3) * 8;     // k-subchunk (8 bf16 = 16B)

    const unsigned short* Arow0 = A + (size_t)(bm * AROWS + r0) * lda + q0;
    const unsigned short* Arow1 = A + (size_t)(bm * AROWS + r0 + 64) * lda + q0;  // MFR==4 only
    const unsigned short* Brow0 = B + (size_t)(bn * 128 + r0) * ldb + q0;
    const unsigned short* Brow1 = B + (size_t)(bn * 128 + r0 + 64) * ldb + q0;

    // prologue: stage k0=0 into buffer 0
    GLD(Arow0, As[0] + tid * 8);
    if constexpr (MFR == 4) GLD(Arow1, As[0] + (tid + 256) * 8);
    GLD(Brow0, Bs[0] + tid * 8);
    GLD(Brow1, Bs[0] + (tid + 256) * 8);
    __syncthreads();

    int cur = 0;
    for (int k0 = 0; k0 < kend; k0 += 32) {
        const int kn = k0 + 32;
        if (kn < kend) {   // issue next tile's stage; latency hides under MFMA below
            GLD(Arow0 + kn, As[cur ^ 1] + tid * 8);
            if constexpr (MFR == 4) GLD(Arow1 + kn, As[cur ^ 1] + (tid + 256) * 8);
            GLD(Brow0 + kn, Bs[cur ^ 1] + tid * 8);
            GLD(Brow1 + kn, Bs[cur ^ 1] + (tid + 256) * 8);
        }
        short8 av[MFR], bv[4];
#pragma unroll
        for (int m = 0; m < MFR; ++m)
            av[m] = *(const short8*)&As[cur][(wm + m * 16 + lo) * 32 + hi8];
#pragma unroll
        for (int n = 0; n < 4; ++n)
            bv[n] = *(const short8*)&Bs[cur][(wn + n * 16 + lo) * 32 + hi8];
#pragma unroll
        for (int m = 0; m < MFR; ++m)
#pragma unroll
            for (int n = 0; n < 4; ++n)
                acc[m][n] = __builtin_amdgcn_mfma_f32_16x16x32_bf16(av[m], bv[n], acc[m][n], 0, 0, 0);
        __syncthreads();   // vmcnt(0) drain: next buffer staged; barrier: reads of cur done
        cur ^= 1;
    }
}

// z=0: Q, z=1: K (row-major bf16 [8192,1024]).
// z=2: V^T via operand swap: C[e][t] = sum_d Wv[e][d] x[t][d] (contiguous stores along t).
__global__ __launch_bounds__(256) void qkv_gemm(const unsigned short* __restrict__ xb,
                                                const unsigned short* __restrict__ wb,
                                                unsigned short* __restrict__ Qb,
                                                unsigned short* __restrict__ Kb,
                                                unsigned short* __restrict__ Vt) {
    const int z = blockIdx.z;
    const int lane = threadIdx.x & 63, wave = threadIdx.x >> 6;
    const int wr = (wave >> 1) * 64 + ((lane >> 4) << 2);
    const int wc = (wave & 1) * 64 + (lane & 15);
    f32x4 acc[4][4] = {};

    if (z < 2) {
        const int bm = blockIdx.x, bn = blockIdx.y;
        const unsigned short* Bp = wb + (size_t)z * D_DIM * D_DIM;
        gemm_core_t<4>(xb, Bp, D_DIM, D_DIM, bm, bn, D_DIM, acc);
        unsigned short* O = (z == 0) ? Qb : Kb;
        const int rb = bm * 128 + wr;
        const int cb = bn * 128 + wc;
#pragma unroll
        for (int m = 0; m < 4; ++m)
#pragma unroll
            for (int n = 0; n < 4; ++n)
#pragma unroll
                for (int r = 0; r < 4; ++r)
                    O[(size_t)(rb + m * 16 + r) * D_DIM + (cb + n * 16)] = f2bf(acc[m][n][r]);
    } else {
        const unsigned short* Av = wb + (size_t)2 * D_DIM * D_DIM;
        gemm_core_t<4>(Av, xb, D_DIM, D_DIM, blockIdx.y, blockIdx.x, D_DIM, acc);
        const int rb = blockIdx.y * 128 + wr;    // e
        const int cb = blockIdx.x * 128 + wc;    // t global
#pragma unroll
        for (int m = 0; m < 4; ++m)
#pragma unroll
            for (int n = 0; n < 4; ++n)
#pragma unroll
                for (int r = 0; r < 4; ++r) {
                    int e = rb + m * 16 + r;
                    int t = cb + n * 16;
                    int b = t >> 11, tt = t & 2047;
                    Vt[((size_t)b * D_DIM + e) * T_SEQ + tt] = f2bf(acc[m][n][r]);
                }
    }
}

// 64x128 tiles: grid (32 m-blocks, 16 n-blocks, 4 batches); causal skip bn > bm/2.
__global__ __launch_bounds__(256) void s_gemm(const unsigned short* __restrict__ Qb,
                                              const unsigned short* __restrict__ Kb,
                                              float* __restrict__ S) {
    const int bm = blockIdx.x, bn = blockIdx.y, z = blockIdx.z;
    if (bn > (bm >> 1)) return;   // tile entirely above the diagonal
    const unsigned short* Ap = Qb + (size_t)z * T_SEQ * D_DIM;
    const unsigned short* Bp = Kb + (size_t)z * T_SEQ * D_DIM;
    f32x4 acc[2][4] = {};
    gemm_core_t<2>(Ap, Bp, D_DIM, D_DIM, bm, bn, D_DIM, acc);

    float* Sp = S + (size_t)z * T_SEQ * T_SEQ;
    const float scale = 0.03125f;  // 1/sqrt(1024)
    const int lane = threadIdx.x & 63, wave = threadIdx.x >> 6;
    const int rb = bm * 64 + (wave >> 1) * 32 + ((lane >> 4) << 2);
    const int cb = bn * 128 + (wave & 1) * 64 + (lane & 15);
#pragma unroll
    for (int m = 0; m < 2; ++m)
#pragma unroll
        for (int n = 0; n < 4; ++n)
#pragma unroll
            for (int r = 0; r < 4; ++r) {
                int row = rb + m * 16 + r;
                int col = cb + n * 16;
                if (col <= row) Sp[(size_t)row * T_SEQ + col] = acc[m][n][r] * scale;
            }
}

__global__ __launch_bounds__(256) void softmax_kernel(const float* __restrict__ S,
                                                      unsigned short* __restrict__ P) {
    const int row = blockIdx.x;          // 0..8191
    const int b = row >> 11, i = row & 2047;
    const float* srow = S + ((size_t)b * T_SEQ + i) * T_SEQ;
    unsigned short* prow = P + ((size_t)b * T_SEQ + i) * T_SEQ;
    __shared__ float buf[T_SEQ];
    __shared__ float red[4];
    const int tid = threadIdx.x, lane = tid & 63, wave = tid >> 6;
    const int len = i + 1;
    const int padlen = ((i >> 7) + 1) * 128;   // pv_gemm reads cols < its kend <= padlen

    float m = -1e30f;
    for (int j = tid; j < len; j += 256) { float s = srow[j]; buf[j] = s; m = fmaxf(m, s); }
#pragma unroll
    for (int off = 32; off; off >>= 1) m = fmaxf(m, __shfl_xor(m, off, 64));
    if (lane == 0) red[wave] = m;
    __syncthreads();
    m = fmaxf(fmaxf(red[0], red[1]), fmaxf(red[2], red[3]));
    __syncthreads();

    float s = 0.f;
    for (int j = tid; j < len; j += 256) { float e = __expf(buf[j] - m); buf[j] = e; s += e; }
#pragma unroll
    for (int off = 32; off; off >>= 1) s += __shfl_xor(s, off, 64);
    if (lane == 0) red[wave] = s;
    __syncthreads();
    s = red[0] + red[1] + red[2] + red[3];
    float inv = 1.f / s;

    for (int j = tid; j < padlen; j += 256)
        prow[j] = (j < len) ? f2bf(buf[j] * inv) : (unsigned short)0;
}

// 64x128 tiles: grid (32 m-blocks, 8 n-blocks, 4 batches); causal K-bound per block row.
__global__ __launch_bounds__(256) void pv_gemm(const unsigned short* __restrict__ P,
                                               const unsigned short* __restrict__ Vt,
                                               float* __restrict__ Out) {
    const int bm = blockIdx.x, bn = blockIdx.y, z = blockIdx.z;
    const unsigned short* Ap = P + (size_t)z * T_SEQ * T_SEQ;
    const unsigned short* Bp = Vt + (size_t)z * D_DIM * T_SEQ;
    f32x4 acc[2][4] = {};
    const int kend = ((bm >> 1) + 1) * 128;   // rows [bm*64, bm*64+63] need keys < kend
    gemm_core_t<2>(Ap, Bp, T_SEQ, T_SEQ, bm, bn, kend, acc);

    float* Op = Out + (size_t)z * T_SEQ * D_DIM;
    const int lane = threadIdx.x & 63, wave = threadIdx.x >> 6;
    const int rb = bm * 64 + (wave >> 1) * 32 + ((lane >> 4) << 2);
    const int cb = bn * 128 + (wave & 1) * 64 + (lane & 15);
#pragma unroll
    for (int m = 0; m < 2; ++m)
#pragma unroll
        for (int n = 0; n < 4; ++n)
#pragma unroll
            for (int r = 0; r < 4; ++r)
                Op[(size_t)(rb + m * 16 + r) * D_DIM + (cb + n * 16)] = acc[m][n][r];
}

extern "C" void kernel_launch(void* const* d_in, const int* in_sizes, int n_in,
                              void* d_out, int out_size, void* d_ws, size_t ws_size,
                              hipStream_t stream) {
    const float* x  = (const float*)d_in[0];
    const float* Wq = (const float*)d_in[1];
    const float* Wk = (const float*)d_in[2];
    const float* Wv = (const float*)d_in[3];
    float* out = (float*)d_out;
    char* ws = (char*)d_ws;

    // workspace layout (bytes)
    unsigned short* xb = (unsigned short*)(ws);                 // 16 MB  x bf16 [8192,1024]
    unsigned short* wb = (unsigned short*)(ws + 16777216);      // 6 MB   Wq|Wk|Wv bf16
    unsigned short* Qb = (unsigned short*)(ws + 23068672);      // 16 MB
    unsigned short* Kb = (unsigned short*)(ws + 39845888);      // 16 MB
    unsigned short* Vt = (unsigned short*)(ws + 56623104);      // 16 MB  V^T per batch [1024][2048]
    float*          S  = (float*)(ws + 73400320);               // 64 MB  scores fp32
    unsigned short* P  = (unsigned short*)(ws + 140509184);     // 32 MB  probs bf16
    (void)ws_size; (void)in_sizes; (void)n_in; (void)out_size;

    cast_kernel<<<8192, 256, 0, stream>>>((const float4*)x,  (ushort4*)xb, 2097152);
    cast_kernel<<<1024, 256, 0, stream>>>((const float4*)Wq, (ushort4*)(wb),           262144);
    cast_kernel<<<1024, 256, 0, stream>>>((const float4*)Wk, (ushort4*)(wb + 1048576), 262144);
    cast_kernel<<<1024, 256, 0, stream>>>((const float4*)Wv, (ushort4*)(wb + 2097152), 262144);

    qkv_gemm<<<dim3(64, 8, 3), 256, 0, stream>>>(xb, wb, Qb, Kb, Vt);
    s_gemm<<<dim3(32, 16, NB), 256, 0, stream>>>(Qb, Kb, S);
    softmax_kernel<<<8192, 256, 0, stream>>>(S, P);
    pv_gemm<<<dim3(32, 8, NB), 256, 0, stream>>>(P, Vt, out);
}

// Round 4
// 172.733 us; speedup vs baseline: 1.2590x; 1.2590x over previous
//
#include <hip/hip_runtime.h>
#include <hip/hip_bf16.h>

#define T_SEQ 2048
#define D_DIM 1024
#define NB 4

typedef __attribute__((ext_vector_type(8))) short short8;
typedef __attribute__((ext_vector_type(4))) float f32x4;

__device__ __forceinline__ unsigned short f2bf(float f) {
    unsigned int u = __float_as_uint(f);
    u = (u + 0x7FFFu + ((u >> 16) & 1u)) >> 16;
    return (unsigned short)u;
}

__global__ void cast_kernel(const float4* __restrict__ in, ushort4* __restrict__ out, int n4) {
    int i = blockIdx.x * 256 + threadIdx.x;
    if (i < n4) {
        float4 f = in[i];
        ushort4 o;
        o.x = f2bf(f.x); o.y = f2bf(f.y); o.z = f2bf(f.z); o.w = f2bf(f.w);
        out[i] = o;
    }
}

#define GLD(gp, lp) __builtin_amdgcn_global_load_lds( \
    (__attribute__((address_space(1))) void*)(gp), \
    (__attribute__((address_space(3))) void*)(lp), 16, 0, 0)

// 128x128 tile, BK=32, 4 waves (2x2, each 64x64 = 4x4 frags of 16x16x32).
// Depth-2 prefetch over 3 LDS buffers with COUNTED vmcnt (T4): steady-state
// vmcnt(8) keeps 2 tiles' loads in flight across barriers — no vmcnt(0) drain.
// LDS bank-conflict fix (T2, m21-legal form): linear GLD dest + inverse-swizzled
// GLOBAL source chunk + swizzled ds_read address; f(row)=(row>>1)&3 on 16B chunks
// turns the 8-way conflict of [R][32]-bf16 rows into a free 2-way.
// Hazards: BAR1 after forced lgkmcnt(0) closes read->write (stage can't overwrite
// a buffer still being read); vmcnt(N)+BAR2 closes write->read (tile t landed in
// all waves before any ds_read of it); sched_barrier(0) pins MFMA below lgkmcnt
// (rule #18) and ds_read below BAR2.
__device__ __forceinline__ void gemm_core(const unsigned short* __restrict__ A,
                                          const unsigned short* __restrict__ B,
                                          int lda, int ldb, int bm, int bn, int kend,
                                          f32x4 acc[4][4]) {
    __shared__ __align__(16) unsigned short As[3][128 * 32];
    __shared__ __align__(16) unsigned short Bs[3][128 * 32];
    const int tid  = threadIdx.x;
    const int lane = tid & 63;
    const int wave = tid >> 6;
    const int wm   = (wave >> 1) * 64;
    const int wn   = (wave & 1) * 64;
    const int lo   = lane & 15;
    const int hi   = lane >> 4;
    const int r0   = tid >> 2;                          // staging row 0..63
    const int q0   = (((tid & 3) ^ ((r0 >> 1) & 3)) * 8);  // swizzled source chunk

    const unsigned short* Arow0 = A + (size_t)(bm * 128 + r0) * lda + q0;
    const unsigned short* Arow1 = A + (size_t)(bm * 128 + r0 + 64) * lda + q0;
    const unsigned short* Brow0 = B + (size_t)(bn * 128 + r0) * ldb + q0;
    const unsigned short* Brow1 = B + (size_t)(bn * 128 + r0 + 64) * ldb + q0;

#define STAGE(t, buf) do { const int kk_ = (t) << 5; \
        GLD(Arow0 + kk_, As[buf] + tid * 8); \
        GLD(Arow1 + kk_, As[buf] + (tid + 256) * 8); \
        GLD(Brow0 + kk_, Bs[buf] + tid * 8); \
        GLD(Brow1 + kk_, Bs[buf] + (tid + 256) * 8); } while (0)

    const int nt = kend >> 5;
    STAGE(0, 0);
    STAGE(1, 1);                                        // 8 loads in flight

    // swizzled read offsets (compile-time-unrolled -> registers)
    int aoff[4], boff[4];
#pragma unroll
    for (int m = 0; m < 4; ++m) {
        const int ra = wm + m * 16 + lo;
        const int rb = wn + m * 16 + lo;
        aoff[m] = ra * 32 + ((hi ^ ((ra >> 1) & 3)) * 8);
        boff[m] = rb * 32 + ((hi ^ ((rb >> 1) & 3)) * 8);
    }

    int cur = 0;
    for (int t = 0; t < nt; ++t) {
        __builtin_amdgcn_s_barrier();        // BAR1: all waves' reads of stage target retired
        if (t + 2 < nt) {
            int nb = cur + 2; if (nb >= 3) nb -= 3;
            STAGE(t + 2, nb);
            asm volatile("s_waitcnt vmcnt(8)" ::: "memory");   // tile t done; t+1,t+2 in flight
        } else if (t + 1 < nt) {
            asm volatile("s_waitcnt vmcnt(4)" ::: "memory");   // tile t done; t+1 in flight
        } else {
            asm volatile("s_waitcnt vmcnt(0)" ::: "memory");   // last tile done
        }
        __builtin_amdgcn_s_barrier();        // BAR2: tile t landed for every wave
        __builtin_amdgcn_sched_barrier(0);   // ds_read must not hoist above BAR2

        short8 av[4], bv[4];
#pragma unroll
        for (int m = 0; m < 4; ++m) av[m] = *(const short8*)&As[cur][aoff[m]];
#pragma unroll
        for (int n = 0; n < 4; ++n) bv[n] = *(const short8*)&Bs[cur][boff[n]];
        asm volatile("s_waitcnt lgkmcnt(0)" ::: "memory");
        __builtin_amdgcn_sched_barrier(0);   // MFMA must not hoist above lgkmcnt (rule #18)

        __builtin_amdgcn_s_setprio(1);
#pragma unroll
        for (int m = 0; m < 4; ++m)
#pragma unroll
            for (int n = 0; n < 4; ++n)
                acc[m][n] = __builtin_amdgcn_mfma_f32_16x16x32_bf16(av[m], bv[n], acc[m][n], 0, 0, 0);
        __builtin_amdgcn_s_setprio(0);

        cur += 1; if (cur >= 3) cur = 0;
    }
#undef STAGE
}

// z=0: Q, z=1: K (row-major bf16 [8192,1024]).
// z=2: V^T via operand swap: C[e][t] = sum_d Wv[e][d] x[t][d] (contiguous stores along t).
__global__ __launch_bounds__(256) void qkv_gemm(const unsigned short* __restrict__ xb,
                                                const unsigned short* __restrict__ wb,
                                                unsigned short* __restrict__ Qb,
                                                unsigned short* __restrict__ Kb,
                                                unsigned short* __restrict__ Vt) {
    const int z = blockIdx.z;
    const int lane = threadIdx.x & 63, wave = threadIdx.x >> 6;
    const int wr = (wave >> 1) * 64 + ((lane >> 4) << 2);
    const int wc = (wave & 1) * 64 + (lane & 15);
    f32x4 acc[4][4] = {};

    if (z < 2) {
        const int bm = blockIdx.x, bn = blockIdx.y;
        const unsigned short* Bp = wb + (size_t)z * D_DIM * D_DIM;
        gemm_core(xb, Bp, D_DIM, D_DIM, bm, bn, D_DIM, acc);
        unsigned short* O = (z == 0) ? Qb : Kb;
        const int rb = bm * 128 + wr;
        const int cb = bn * 128 + wc;
#pragma unroll
        for (int m = 0; m < 4; ++m)
#pragma unroll
            for (int n = 0; n < 4; ++n)
#pragma unroll
                for (int r = 0; r < 4; ++r)
                    O[(size_t)(rb + m * 16 + r) * D_DIM + (cb + n * 16)] = f2bf(acc[m][n][r]);
    } else {
        const unsigned short* Av = wb + (size_t)2 * D_DIM * D_DIM;
        gemm_core(Av, xb, D_DIM, D_DIM, blockIdx.y, blockIdx.x, D_DIM, acc);
        const int rb = blockIdx.y * 128 + wr;    // e
        const int cb = blockIdx.x * 128 + wc;    // t global
#pragma unroll
        for (int m = 0; m < 4; ++m)
#pragma unroll
            for (int n = 0; n < 4; ++n)
#pragma unroll
                for (int r = 0; r < 4; ++r) {
                    int e = rb + m * 16 + r;
                    int t = cb + n * 16;
                    int b = t >> 11, tt = t & 2047;
                    Vt[((size_t)b * D_DIM + e) * T_SEQ + tt] = f2bf(acc[m][n][r]);
                }
    }
}

// Flat grid of exactly 544 working tiles (136 causal tiles x 4 batches), no dead blocks.
// d%8 -> XCD (assumed round-robin): batch = (d&7)>>1 pins each batch to an XCD pair;
// triangle index iterated bm-major so consecutive tiles on an XCD share the Q-panel (L2-hot).
__global__ __launch_bounds__(256) void s_gemm(const unsigned short* __restrict__ Qb,
                                              const unsigned short* __restrict__ Kb,
                                              float* __restrict__ S) {
    const int d = blockIdx.x;
    const int j = d & 7;
    const int z = j >> 1;
    int i = (j & 1) * 68 + (d >> 3);     // triangle index 0..135
    int bm = 0;
    while (i >= bm + 1) { i -= (bm + 1); ++bm; }
    const int bn = i;                    // bn <= bm

    const unsigned short* Ap = Qb + (size_t)z * T_SEQ * D_DIM;
    const unsigned short* Bp = Kb + (size_t)z * T_SEQ * D_DIM;
    f32x4 acc[4][4] = {};
    gemm_core(Ap, Bp, D_DIM, D_DIM, bm, bn, D_DIM, acc);

    float* Sp = S + (size_t)z * T_SEQ * T_SEQ;
    const float scale = 0.03125f;  // 1/sqrt(1024)
    const int lane = threadIdx.x & 63, wave = threadIdx.x >> 6;
    const int rb = bm * 128 + (wave >> 1) * 64 + ((lane >> 4) << 2);
    const int cb = bn * 128 + (wave & 1) * 64 + (lane & 15);
#pragma unroll
    for (int m = 0; m < 4; ++m)
#pragma unroll
        for (int n = 0; n < 4; ++n)
#pragma unroll
            for (int r = 0; r < 4; ++r) {
                int row = rb + m * 16 + r;
                int col = cb + n * 16;
                if (col <= row) Sp[(size_t)row * T_SEQ + col] = acc[m][n][r] * scale;
            }
}

__global__ __launch_bounds__(256) void softmax_kernel(const float* __restrict__ S,
                                                      unsigned short* __restrict__ P) {
    const int row = blockIdx.x;          // 0..8191
    const int b = row >> 11, i = row & 2047;
    const float* srow = S + ((size_t)b * T_SEQ + i) * T_SEQ;
    unsigned short* prow = P + ((size_t)b * T_SEQ + i) * T_SEQ;
    __shared__ float buf[T_SEQ];
    __shared__ float red[4];
    const int tid = threadIdx.x, lane = tid & 63, wave = tid >> 6;
    const int len = i + 1;
    const int padlen = ((i >> 7) + 1) * 128;   // pv_gemm reads cols < kend = padlen

    float m = -1e30f;
    for (int j = tid; j < len; j += 256) { float s = srow[j]; buf[j] = s; m = fmaxf(m, s); }
#pragma unroll
    for (int off = 32; off; off >>= 1) m = fmaxf(m, __shfl_xor(m, off, 64));
    if (lane == 0) red[wave] = m;
    __syncthreads();
    m = fmaxf(fmaxf(red[0], red[1]), fmaxf(red[2], red[3]));
    __syncthreads();

    float s = 0.f;
    for (int j = tid; j < len; j += 256) { float e = __expf(buf[j] - m); buf[j] = e; s += e; }
#pragma unroll
    for (int off = 32; off; off >>= 1) s += __shfl_xor(s, off, 64);
    if (lane == 0) red[wave] = s;
    __syncthreads();
    s = red[0] + red[1] + red[2] + red[3];
    float inv = 1.f / s;

    for (int j = tid; j < padlen; j += 256)
        prow[j] = (j < len) ? f2bf(buf[j] * inv) : (unsigned short)0;
}

// Flat grid of 512 (16 bm x 8 bn x 4 batches), batch pinned to XCD pair, bn-inner
// so consecutive tiles share the P-panel; causal K-bound kend=(bm+1)*128.
__global__ __launch_bounds__(256) void pv_gemm(const unsigned short* __restrict__ P,
                                               const unsigned short* __restrict__ Vt,
                                               float* __restrict__ Out) {
    const int d = blockIdx.x;
    const int j = d & 7;
    const int z = j >> 1;
    const int t = (j & 1) * 64 + (d >> 3);   // 0..127
    const int bm = t >> 3, bn = t & 7;

    const unsigned short* Ap = P + (size_t)z * T_SEQ * T_SEQ;
    const unsigned short* Bp = Vt + (size_t)z * D_DIM * T_SEQ;
    f32x4 acc[4][4] = {};
    gemm_core(Ap, Bp, T_SEQ, T_SEQ, bm, bn, (bm + 1) * 128, acc);

    float* Op = Out + (size_t)z * T_SEQ * D_DIM;
    const int lane = threadIdx.x & 63, wave = threadIdx.x >> 6;
    const int rb = bm * 128 + (wave >> 1) * 64 + ((lane >> 4) << 2);
    const int cb = bn * 128 + (wave & 1) * 64 + (lane & 15);
#pragma unroll
    for (int m = 0; m < 4; ++m)
#pragma unroll
        for (int n = 0; n < 4; ++n)
#pragma unroll
            for (int r = 0; r < 4; ++r)
                Op[(size_t)(rb + m * 16 + r) * D_DIM + (cb + n * 16)] = acc[m][n][r];
}

extern "C" void kernel_launch(void* const* d_in, const int* in_sizes, int n_in,
                              void* d_out, int out_size, void* d_ws, size_t ws_size,
                              hipStream_t stream) {
    const float* x  = (const float*)d_in[0];
    const float* Wq = (const float*)d_in[1];
    const float* Wk = (const float*)d_in[2];
    const float* Wv = (const float*)d_in[3];
    float* out = (float*)d_out;
    char* ws = (char*)d_ws;

    // workspace layout (bytes)
    unsigned short* xb = (unsigned short*)(ws);                 // 16 MB  x bf16 [8192,1024]
    unsigned short* wb = (unsigned short*)(ws + 16777216);      // 6 MB   Wq|Wk|Wv bf16
    unsigned short* Qb = (unsigned short*)(ws + 23068672);      // 16 MB
    unsigned short* Kb = (unsigned short*)(ws + 39845888);      // 16 MB
    unsigned short* Vt = (unsigned short*)(ws + 56623104);      // 16 MB  V^T per batch [1024][2048]
    float*          S  = (float*)(ws + 73400320);               // 64 MB  scores fp32
    unsigned short* P  = (unsigned short*)(ws + 140509184);     // 32 MB  probs bf16
    (void)ws_size; (void)in_sizes; (void)n_in; (void)out_size;

    cast_kernel<<<8192, 256, 0, stream>>>((const float4*)x,  (ushort4*)xb, 2097152);
    cast_kernel<<<1024, 256, 0, stream>>>((const float4*)Wq, (ushort4*)(wb),           262144);
    cast_kernel<<<1024, 256, 0, stream>>>((const float4*)Wk, (ushort4*)(wb + 1048576), 262144);
    cast_kernel<<<1024, 256, 0, stream>>>((const float4*)Wv, (ushort4*)(wb + 2097152), 262144);

    qkv_gemm<<<dim3(64, 8, 3), 256, 0, stream>>>(xb, wb, Qb, Kb, Vt);
    s_gemm<<<544, 256, 0, stream>>>(Qb, Kb, S);
    softmax_kernel<<<8192, 256, 0, stream>>>(S, P);
    pv_gemm<<<512, 256, 0, stream>>>(P, Vt, out);
}